// Round 1
// baseline (713.151 us; speedup 1.0000x reference)
//
#include <hip/hip_runtime.h>

// SpatialEvoProp: per-edge distance-bucket embeddings + gated aggregation.
// Inputs (f32 unless noted):
//  0 feat [N,64]  1 loc [N,2]  2 embed_table [65,32]  3 G_w [64,32]
//  4 agg_w [64,128]  5 agg_b [64]  6 boundaries [64]
//  7 src [E] i32  8 dst [E] i32  9 inter_ids [E,5] i32
// Output: rst [N,64] f32 (scatter-sum over dst).

#define DFEAT 64

// ---- zero output + degree arrays ------------------------------------------
__global__ void k_zero(float* __restrict__ rst, float* __restrict__ degs,
                       int nRst, int nDeg) {
    int i = blockIdx.x * blockDim.x + threadIdx.x;
    if (i < nRst) rst[i] = 0.0f;
    if (i < nDeg) degs[i] = 0.0f;
}

// ---- degree counting -------------------------------------------------------
__global__ void k_deg(const int* __restrict__ src, const int* __restrict__ dst,
                      float* __restrict__ deg_in, float* __restrict__ deg_out,
                      int E) {
    int i = blockIdx.x * blockDim.x + threadIdx.x;
    if (i < E) {
        atomicAdd(&deg_in[dst[i]], 1.0f);
        atomicAdd(&deg_out[src[i]], 1.0f);
    }
}

// ---- deg -> clamp(1) -> rsqrt (in place, contiguous 2N) --------------------
__global__ void k_norm(float* __restrict__ degs, int n) {
    int i = blockIdx.x * blockDim.x + threadIdx.x;
    if (i < n) degs[i] = rsqrtf(fmaxf(degs[i], 1.0f));
}

// ---- P = embed_table @ G_w.T : [65,64] ------------------------------------
__global__ void k_P(const float* __restrict__ Etab, const float* __restrict__ G,
                    float* __restrict__ P) {
    int i = blockIdx.x * blockDim.x + threadIdx.x;
    if (i < 65 * DFEAT) {
        int b = i >> 6, o = i & 63;
        float a = 0.0f;
#pragma unroll
        for (int m = 0; m < 32; ++m)
            a = fmaf(Etab[b * 32 + m], G[o * 32 + m], a);
        P[i] = a;
    }
}

// ---- main edge kernel: one wave per edge, lane = output feature -----------
__global__ __launch_bounds__(64) void k_edge(
    const float* __restrict__ feat, const float* __restrict__ loc,
    const float* __restrict__ agg_w, const float* __restrict__ agg_b,
    const float* __restrict__ bnds, const int* __restrict__ src,
    const int* __restrict__ dst, const int* __restrict__ inter,
    const float* __restrict__ P, const float* __restrict__ d0,
    const float* __restrict__ d2, float* __restrict__ rst, int E) {
    const int lane = threadIdx.x;  // 0..63

    // persistent per-lane state (amortized over ~E/gridDim edges)
    const float bnd = bnds[lane];       // boundary value for ballot-bucketize
    const float bias = agg_b[lane];
    float w[128];                       // agg_w row `lane` in VGPRs
    {
        const float4* wrow = (const float4*)(agg_w + (size_t)lane * 128);
#pragma unroll
        for (int t = 0; t < 32; ++t) {
            float4 q = wrow[t];
            w[4 * t + 0] = q.x; w[4 * t + 1] = q.y;
            w[4 * t + 2] = q.z; w[4 * t + 3] = q.w;
        }
    }

    __shared__ float sc[128];  // single-wave block: barriers are cheap

    for (int e = blockIdx.x; e < E; e += gridDim.x) {
        const int s = src[e];
        const int d = dst[e];
        const float2 ls = ((const float2*)loc)[s];
        const float2 ld = ((const float2*)loc)[d];

        // dist(dst, src) -> bucket via ballot (count of boundaries < x)
        float dx = ld.x - ls.x, dy = ld.y - ls.y;
        float dist1 = sqrtf(dx * dx + dy * dy);
        int b1 = __popcll(__ballot(bnd < dist1));

        // u[k] = P[b1][k] * feat[src][k]   (coalesced 256B rows)
        float u = P[(size_t)b1 * DFEAT + lane] * feat[(size_t)s * DFEAT + lane];

        // v[k] = mean_j P[bj][k] * feat[ij][k]
        float v = 0.0f;
#pragma unroll
        for (int j = 0; j < 5; ++j) {
            int ij = inter[(size_t)e * 5 + j];
            float2 lj = ((const float2*)loc)[ij];
            float ex = ls.x - lj.x, ey = ls.y - lj.y;
            float dj = sqrtf(ex * ex + ey * ey);
            int bj = __popcll(__ballot(bnd < dj));
            v = fmaf(P[(size_t)bj * DFEAT + lane],
                     feat[(size_t)ij * DFEAT + lane], v);
        }
        v *= 0.2f;

        __syncthreads();  // WAR: previous iteration's readers done
        sc[lane] = u;
        sc[64 + lane] = v;
        __syncthreads();

        // h[lane] = bias + sum_k W[lane][k] * cat[k]
        float acc = bias;
        const float4* sc4 = (const float4*)sc;
#pragma unroll
        for (int t = 0; t < 32; ++t) {
            float4 c = sc4[t];  // broadcast read, conflict-free
            acc = fmaf(w[4 * t + 0], c.x, acc);
            acc = fmaf(w[4 * t + 1], c.y, acc);
            acc = fmaf(w[4 * t + 2], c.z, acc);
            acc = fmaf(w[4 * t + 3], c.w, acc);
        }

        const float scale = d0[d] * d2[s];
        atomicAdd(&rst[(size_t)d * DFEAT + lane], scale * acc);
    }
}

extern "C" void kernel_launch(void* const* d_in, const int* in_sizes, int n_in,
                              void* d_out, int out_size, void* d_ws,
                              size_t ws_size, hipStream_t stream) {
    const float* feat  = (const float*)d_in[0];
    const float* loc   = (const float*)d_in[1];
    const float* embed = (const float*)d_in[2];
    const float* G_w   = (const float*)d_in[3];
    const float* agg_w = (const float*)d_in[4];
    const float* agg_b = (const float*)d_in[5];
    const float* bnds  = (const float*)d_in[6];
    const int* src   = (const int*)d_in[7];
    const int* dst   = (const int*)d_in[8];
    const int* inter = (const int*)d_in[9];

    const int N = in_sizes[0] / DFEAT;
    const int E = in_sizes[7];

    float* rst = (float*)d_out;
    float* ws = (float*)d_ws;
    float* deg_in = ws;            // [N]  -> becomes d0
    float* deg_out = ws + N;       // [N]  -> becomes d2
    float* P = ws + 2 * (size_t)N; // [65*64]

    const int nRst = N * DFEAT;
    const int nDeg = 2 * N;

    k_zero<<<(nRst + 255) / 256, 256, 0, stream>>>(rst, deg_in, nRst, nDeg);
    k_deg<<<(E + 255) / 256, 256, 0, stream>>>(src, dst, deg_in, deg_out, E);
    k_norm<<<(nDeg + 255) / 256, 256, 0, stream>>>(deg_in, nDeg);
    k_P<<<(65 * DFEAT + 255) / 256, 256, 0, stream>>>(embed, G_w, P);
    k_edge<<<4096, 64, 0, stream>>>(feat, loc, agg_w, agg_b, bnds, src, dst,
                                    inter, P, deg_in, deg_out, rst, E);
}

// Round 2
// 481.322 us; speedup vs baseline: 1.4817x; 1.4817x over previous
//
#include <hip/hip_runtime.h>

// SpatialEvoProp: per-edge distance-bucket embeddings + gated aggregation.
// Inputs (f32 unless noted):
//  0 feat [N,64]  1 loc [N,2]  2 embed_table [65,32]  3 G_w [64,32]
//  4 agg_w [64,128]  5 agg_b [64]  6 boundaries [64]
//  7 src [E] i32  8 dst [E] i32  9 inter_ids [E,5] i32
// Output: rst [N,64] f32 (scatter-sum over dst).
//
// R1 -> R2: VGPR=80 showed agg_w was re-streamed from L1 every edge
// (~32KB/edge/wave). Force 170-VGPR budget so w[128] stays register
// resident; 4-wave blocks; 8-way acc split; P table in LDS.

#define DFEAT 64

__global__ void k_zero(float* __restrict__ rst, float* __restrict__ degs,
                       int nRst, int nDeg) {
    int i = blockIdx.x * blockDim.x + threadIdx.x;
    if (i < nRst) rst[i] = 0.0f;
    if (i < nDeg) degs[i] = 0.0f;
}

__global__ void k_deg(const int* __restrict__ src, const int* __restrict__ dst,
                      float* __restrict__ deg_in, float* __restrict__ deg_out,
                      int E) {
    int i = blockIdx.x * blockDim.x + threadIdx.x;
    if (i < E) {
        atomicAdd(&deg_in[dst[i]], 1.0f);
        atomicAdd(&deg_out[src[i]], 1.0f);
    }
}

__global__ void k_norm(float* __restrict__ degs, int n) {
    int i = blockIdx.x * blockDim.x + threadIdx.x;
    if (i < n) degs[i] = rsqrtf(fmaxf(degs[i], 1.0f));
}

// P = embed_table @ G_w.T : [65,64]
__global__ void k_P(const float* __restrict__ Etab, const float* __restrict__ G,
                    float* __restrict__ P) {
    int i = blockIdx.x * blockDim.x + threadIdx.x;
    if (i < 65 * DFEAT) {
        int b = i >> 6, o = i & 63;
        float a = 0.0f;
#pragma unroll
        for (int m = 0; m < 32; ++m)
            a = fmaf(Etab[b * 32 + m], G[o * 32 + m], a);
        P[i] = a;
    }
}

// main edge kernel: 4 waves/block, one edge stream per wave, lane = feature.
// __launch_bounds__(256,3): min 3 waves/EU -> VGPR cap 170 -> w4[32] stays
// register-resident (R1's VGPR=80 meant agg_w was re-fetched every edge).
__global__ __launch_bounds__(256, 3) void k_edge(
    const float* __restrict__ feat, const float* __restrict__ loc,
    const float* __restrict__ agg_w, const float* __restrict__ agg_b,
    const float* __restrict__ bnds, const int* __restrict__ src,
    const int* __restrict__ dst, const int* __restrict__ inter,
    const float* __restrict__ P, const float* __restrict__ d0,
    const float* __restrict__ d2, float* __restrict__ rst, int E) {
    const int tid = threadIdx.x;
    const int wid = tid >> 6;
    const int lane = tid & 63;

    __shared__ float sP[65 * DFEAT];   // dist-bucket embedding @ G_w.T
    __shared__ float sc[4][2 * DFEAT]; // per-wave cat bounce

    for (int i = tid; i < 65 * DFEAT; i += 256) sP[i] = P[i];

    const float bnd = bnds[lane];   // boundary for ballot-bucketize
    const float bias = agg_b[lane];
    float4 w4[32];                  // agg_w row `lane`, register-resident
    {
        const float4* wrow = (const float4*)(agg_w + (lane << 7));
#pragma unroll
        for (int t = 0; t < 32; ++t) w4[t] = wrow[t];
    }
    float* myc = sc[wid];
    __syncthreads();  // sP ready

    const int stride = gridDim.x << 2;
    for (int eb = (blockIdx.x << 2); eb < E; eb += stride) {
        const int e = eb + wid;            // this wave's edge
        const bool active = (e < E);
        const int ce = active ? e : 0;

        const int s = src[ce];
        const int d = dst[ce];
        int ij[5];
#pragma unroll
        for (int j = 0; j < 5; ++j) ij[j] = inter[ce * 5 + j];

        const float2 ls = ((const float2*)loc)[s];
        const float2 ldd = ((const float2*)loc)[d];
        float2 lj[5];
#pragma unroll
        for (int j = 0; j < 5; ++j) lj[j] = ((const float2*)loc)[ij[j]];
        const float dsc = d0[d] * d2[s];   // issued early, used at the end

        // bucket = count(boundaries < dist)  (searchsorted side='left')
        float dx = ldd.x - ls.x, dy = ldd.y - ls.y;
        const int b1 = __popcll(__ballot(bnd < sqrtf(dx * dx + dy * dy)));
        float u = sP[(b1 << 6) + lane] * feat[(s << 6) + lane];

        float v = 0.0f;
#pragma unroll
        for (int j = 0; j < 5; ++j) {
            float ex = ls.x - lj[j].x, ey = ls.y - lj[j].y;
            const int bj = __popcll(__ballot(bnd < sqrtf(ex * ex + ey * ey)));
            v = fmaf(sP[(bj << 6) + lane], feat[(ij[j] << 6) + lane], v);
        }
        v *= 0.2f;

        __syncthreads();   // WAR: previous iteration's c4 readers done
        myc[lane] = u;
        myc[DFEAT + lane] = v;
        __syncthreads();   // cat visible

        // h[lane] = bias + W[lane][:] . cat  (8-way split chain)
        float acc[8] = {bias, 0.f, 0.f, 0.f, 0.f, 0.f, 0.f, 0.f};
        const float4* c4 = (const float4*)myc;
#pragma unroll
        for (int t = 0; t < 32; ++t) {
            const float4 c = c4[t];   // broadcast LDS read, conflict-free
            const float4 wv = w4[t];
            float a = acc[t & 7];
            a = fmaf(wv.x, c.x, a);
            a = fmaf(wv.y, c.y, a);
            a = fmaf(wv.z, c.z, a);
            a = fmaf(wv.w, c.w, a);
            acc[t & 7] = a;
        }
        if (active) {
            float h = ((acc[0] + acc[1]) + (acc[2] + acc[3])) +
                      ((acc[4] + acc[5]) + (acc[6] + acc[7]));
            atomicAdd(&rst[(d << 6) + lane], dsc * h);
        }
    }
}

extern "C" void kernel_launch(void* const* d_in, const int* in_sizes, int n_in,
                              void* d_out, int out_size, void* d_ws,
                              size_t ws_size, hipStream_t stream) {
    const float* feat  = (const float*)d_in[0];
    const float* loc   = (const float*)d_in[1];
    const float* embed = (const float*)d_in[2];
    const float* G_w   = (const float*)d_in[3];
    const float* agg_w = (const float*)d_in[4];
    const float* agg_b = (const float*)d_in[5];
    const float* bnds  = (const float*)d_in[6];
    const int* src   = (const int*)d_in[7];
    const int* dst   = (const int*)d_in[8];
    const int* inter = (const int*)d_in[9];

    const int N = in_sizes[0] / DFEAT;
    const int E = in_sizes[7];

    float* rst = (float*)d_out;
    float* ws = (float*)d_ws;
    float* deg_in = ws;            // [N] -> d0
    float* deg_out = ws + N;       // [N] -> d2
    float* P = ws + 2 * (size_t)N; // [65*64]

    const int nRst = N * DFEAT;
    const int nDeg = 2 * N;

    k_zero<<<(nRst + 255) / 256, 256, 0, stream>>>(rst, deg_in, nRst, nDeg);
    k_deg<<<(E + 255) / 256, 256, 0, stream>>>(src, dst, deg_in, deg_out, E);
    k_norm<<<(nDeg + 255) / 256, 256, 0, stream>>>(deg_in, nDeg);
    k_P<<<(65 * DFEAT + 255) / 256, 256, 0, stream>>>(embed, G_w, P);
    // 768 blocks = 3 blocks/CU * 256 CU resident exactly (4 waves/block)
    k_edge<<<768, 256, 0, stream>>>(feat, loc, agg_w, agg_b, bnds, src, dst,
                                    inter, P, deg_in, deg_out, rst, E);
}

// Round 3
// 327.269 us; speedup vs baseline: 2.1791x; 1.4707x over previous
//
#include <hip/hip_runtime.h>

// SpatialEvoProp — R3: MFMA reformulation.
// h[E,64] = cat[E,128] @ W^T is a GEMM: per wave, 16 edges = one M=16 tile of
// mfma_f32_16x16x32_bf16, K=128 (4 slabs), N=64 (4 tiles). Both operands
// split hi/lo bf16, 3-product scheme => f32-grade accuracy.
// A-fragments are built directly in registers (lane = edge(lane&15) x
// k-octet(quad*8)); W fragments live in LDS (ds_read_b128, lane*16B —
// immune to the R1/R2 register-demotion problem).

#define DFEAT 64

typedef __attribute__((ext_vector_type(8))) short short8;
typedef __attribute__((ext_vector_type(4))) float floatx4;

__device__ __forceinline__ short bf16h(float x) {
    unsigned u = __float_as_uint(x);
    return (short)((u + 0x7FFFu + ((u >> 16) & 1u)) >> 16);
}
__device__ __forceinline__ float bf16tof(short h) {
    return __uint_as_float(((unsigned)(unsigned short)h) << 16);
}

// count(boundaries < x): analytic seed + shuffle-verified walk vs the real
// table values (lane L holds boundaries[L]); exact for |seed error| <= 2.
__device__ __forceinline__ int bucketize(float x, float bnd) {
    int i = (int)(x * 31.5f);           // boundaries ~ j/31.5
    i = min(max(i, 0), 64);
#pragma unroll
    for (int t = 0; t < 3; ++t) {
        float bi = __shfl(bnd, min(i, 63));
        if (i < 64 && bi < x) ++i;
    }
#pragma unroll
    for (int t = 0; t < 2; ++t) {
        float bim = __shfl(bnd, max(i - 1, 0));
        if (i > 0 && bim >= x) --i;
    }
    return i;
}

// init: zero rst + degree counters, and compute P = embed @ G_w.T ([65,64])
__global__ void k_init(const float* __restrict__ Etab,
                       const float* __restrict__ G, float* __restrict__ P,
                       float* __restrict__ rst, float* __restrict__ degs,
                       int nRst, int nDeg) {
    int i = blockIdx.x * blockDim.x + threadIdx.x;
    if (i < nRst) rst[i] = 0.0f;
    if (i < nDeg) degs[i] = 0.0f;
    if (i < 65 * DFEAT) {
        int b = i >> 6, o = i & 63;
        float a = 0.0f;
#pragma unroll
        for (int m = 0; m < 32; ++m)
            a = fmaf(Etab[b * 32 + m], G[o * 32 + m], a);
        P[i] = a;
    }
}

__global__ void k_deg(const int* __restrict__ src, const int* __restrict__ dst,
                      float* __restrict__ degs, int N, int E) {
    int i = blockIdx.x * blockDim.x + threadIdx.x;
    if (i < E) {
        atomicAdd(&degs[dst[i]], 1.0f);       // in-deg
        atomicAdd(&degs[N + src[i]], 1.0f);   // out-deg
    }
}

#define PPAD 68  // sP row stride: 68%32=4 banks -> b1-dependent bank spread

__global__ __launch_bounds__(256, 3) void k_edge(
    const float* __restrict__ feat, const float* __restrict__ loc,
    const float* __restrict__ agg_w, const float* __restrict__ agg_b,
    const float* __restrict__ bnds, const int* __restrict__ src,
    const int* __restrict__ dst, const int* __restrict__ inter,
    const float* __restrict__ P, const float* __restrict__ degs,
    float* __restrict__ rst, int N, int E) {
    const int tid = threadIdx.x;
    const int lane = tid & 63;
    const int wid = tid >> 6;
    const int m16 = lane & 15;
    const int quad = lane >> 4;

    __shared__ float sP[65 * PPAD];     // 17680 B
    __shared__ short8 sWBh[16 * 64];    // 16384 B  B-frag (hi)
    __shared__ short8 sWBl[16 * 64];    // 16384 B  B-frag (lo)

    for (int i = tid; i < 65 * DFEAT; i += 256)
        sP[(i >> 6) * PPAD + (i & 63)] = P[i];

    // B-fragment fill: frag f = slab*4+ntile; lane holds n=nt*16+m16,
    // k = slab*32 + quad*8 + j  (B[k][n] = W^T[k][n] = W[n][k])
    for (int f = wid; f < 16; f += 4) {
        int sl = f >> 2, nt = f & 3;
        const float* wp = agg_w + (nt * 16 + m16) * 128 + sl * 32 + quad * 8;
        floatx4 wa = *(const floatx4*)wp;
        floatx4 wb = *(const floatx4*)(wp + 4);
        float xs[8] = {wa.x, wa.y, wa.z, wa.w, wb.x, wb.y, wb.z, wb.w};
        short8 h, l;
#pragma unroll
        for (int j = 0; j < 8; ++j) {
            short hh = bf16h(xs[j]);
            h[j] = hh;
            l[j] = bf16h(xs[j] - bf16tof(hh));
        }
        sWBh[f * 64 + lane] = h;
        sWBl[f * 64 + lane] = l;
    }

    const float bnd = bnds[lane];
    float bias4[4];
#pragma unroll
    for (int nt = 0; nt < 4; ++nt) bias4[nt] = agg_b[nt * 16 + m16];

    __syncthreads();

    const int nstream = gridDim.x << 2;
    const int wstream = (blockIdx.x << 2) + wid;
    const int ngroups = (E + 15) >> 4;

    for (int g = wstream; g < ngroups; g += nstream) {
        const int em = (g << 4) + m16;        // this lane's edge (dup x4)
        const bool act = em < E;
        const int ec = act ? em : 0;

        const int s = src[ec];
        const int d = dst[ec];
        const float2 ls = ((const float2*)loc)[s];
        const float2 ld = ((const float2*)loc)[d];
        float dsc = rsqrtf(fmaxf(degs[d], 1.0f)) *
                    rsqrtf(fmaxf(degs[N + s], 1.0f));
        if (!act) dsc = 0.0f;

        float dx = ld.x - ls.x, dy = ld.y - ls.y;
        const int b1 = bucketize(sqrtf(dx * dx + dy * dy), bnd);

        int ij[5], bj[5];
#pragma unroll
        for (int j = 0; j < 5; ++j) {
            int id = inter[ec * 5 + j];
            ij[j] = id;
            float2 lj = ((const float2*)loc)[id];
            float ex = ls.x - lj.x, ey = ls.y - lj.y;
            bj[j] = bucketize(sqrtf(ex * ex + ey * ey), bnd);
        }

        // ---- build A fragments in registers -------------------------------
        short8 Ah[4], Al[4];
        {
            const float* frow = feat + (s << 6);
            const float* prow = sP + b1 * PPAD;
#pragma unroll
            for (int sl = 0; sl < 2; ++sl) {      // u: cat[k<64]
                int k0 = sl * 32 + quad * 8;
                floatx4 fa = *(const floatx4*)(frow + k0);
                floatx4 fb = *(const floatx4*)(frow + k0 + 4);
                floatx4 pa = *(const floatx4*)(prow + k0);
                floatx4 pb = *(const floatx4*)(prow + k0 + 4);
                float xs[8] = {fa.x * pa.x, fa.y * pa.y, fa.z * pa.z,
                               fa.w * pa.w, fb.x * pb.x, fb.y * pb.y,
                               fb.z * pb.z, fb.w * pb.w};
                short8 h, l;
#pragma unroll
                for (int j = 0; j < 8; ++j) {
                    short hh = bf16h(xs[j]);
                    h[j] = hh;
                    l[j] = bf16h(xs[j] - bf16tof(hh));
                }
                Ah[sl] = h;
                Al[sl] = l;
            }
        }
#pragma unroll
        for (int sl = 0; sl < 2; ++sl) {          // v: cat[k>=64]
            int k0 = sl * 32 + quad * 8;
            float r[8] = {0, 0, 0, 0, 0, 0, 0, 0};
#pragma unroll
            for (int j = 0; j < 5; ++j) {
                const float* fr = feat + (ij[j] << 6);
                const float* pr = sP + bj[j] * PPAD;
                floatx4 fa = *(const floatx4*)(fr + k0);
                floatx4 fb = *(const floatx4*)(fr + k0 + 4);
                floatx4 pa = *(const floatx4*)(pr + k0);
                floatx4 pb = *(const floatx4*)(pr + k0 + 4);
                r[0] = fmaf(fa.x, pa.x, r[0]);
                r[1] = fmaf(fa.y, pa.y, r[1]);
                r[2] = fmaf(fa.z, pa.z, r[2]);
                r[3] = fmaf(fa.w, pa.w, r[3]);
                r[4] = fmaf(fb.x, pb.x, r[4]);
                r[5] = fmaf(fb.y, pb.y, r[5]);
                r[6] = fmaf(fb.z, pb.z, r[6]);
                r[7] = fmaf(fb.w, pb.w, r[7]);
            }
            short8 h, l;
#pragma unroll
            for (int j = 0; j < 8; ++j) {
                float x = r[j] * 0.2f;
                short hh = bf16h(x);
                h[j] = hh;
                l[j] = bf16h(x - bf16tof(hh));
            }
            Ah[2 + sl] = h;
            Al[2 + sl] = l;
        }

        // ---- MFMA: 4 k-slabs x 4 n-tiles x 3 products ---------------------
        floatx4 acc[4] = {{0, 0, 0, 0}, {0, 0, 0, 0}, {0, 0, 0, 0}, {0, 0, 0, 0}};
#pragma unroll
        for (int sl = 0; sl < 4; ++sl) {
#pragma unroll
            for (int nt = 0; nt < 4; ++nt) {
                short8 bh = sWBh[((sl << 2) + nt) * 64 + lane];
                short8 bl = sWBl[((sl << 2) + nt) * 64 + lane];
                acc[nt] = __builtin_amdgcn_mfma_f32_16x16x32_bf16(
                    Ah[sl], bh, acc[nt], 0, 0, 0);
                acc[nt] = __builtin_amdgcn_mfma_f32_16x16x32_bf16(
                    Al[sl], bh, acc[nt], 0, 0, 0);
                acc[nt] = __builtin_amdgcn_mfma_f32_16x16x32_bf16(
                    Ah[sl], bl, acc[nt], 0, 0, 0);
            }
        }

        // ---- epilogue: C row = quad*4+r (edge), col = nt*16+m16 (feature) -
#pragma unroll
        for (int r = 0; r < 4; ++r) {
            const int m = (quad << 2) + r;
            const int dm = __shfl(d, m);
            const float sc = __shfl(dsc, m);
#pragma unroll
            for (int nt = 0; nt < 4; ++nt) {
                float val = (acc[nt][r] + bias4[nt]) * sc;
                atomicAdd(&rst[(dm << 6) + nt * 16 + m16], val);
            }
        }
    }
}

extern "C" void kernel_launch(void* const* d_in, const int* in_sizes, int n_in,
                              void* d_out, int out_size, void* d_ws,
                              size_t ws_size, hipStream_t stream) {
    const float* feat  = (const float*)d_in[0];
    const float* loc   = (const float*)d_in[1];
    const float* embed = (const float*)d_in[2];
    const float* G_w   = (const float*)d_in[3];
    const float* agg_w = (const float*)d_in[4];
    const float* agg_b = (const float*)d_in[5];
    const float* bnds  = (const float*)d_in[6];
    const int* src   = (const int*)d_in[7];
    const int* dst   = (const int*)d_in[8];
    const int* inter = (const int*)d_in[9];

    const int N = in_sizes[0] / DFEAT;
    const int E = in_sizes[7];

    float* rst = (float*)d_out;
    float* ws = (float*)d_ws;
    float* degs = ws;               // [2N]: [0,N)=in-deg, [N,2N)=out-deg
    float* P = ws + 2 * (size_t)N;  // [65*64]

    const int nRst = N * DFEAT;
    const int nDeg = 2 * N;

    k_init<<<(nRst + 255) / 256, 256, 0, stream>>>(embed, G_w, P, rst, degs,
                                                   nRst, nDeg);
    k_deg<<<(E + 255) / 256, 256, 0, stream>>>(src, dst, degs, N, E);
    // LDS 50448 B/block -> 3 blocks/CU; 768 blocks = exactly resident
    k_edge<<<768, 256, 0, stream>>>(feat, loc, agg_w, agg_b, bnds, src, dst,
                                    inter, P, degs, rst, N, E);
}